// Round 13
// baseline (68.045 us; speedup 1.0000x reference)
//
#include <hip/hip_runtime.h>

typedef unsigned char u8;
typedef __attribute__((ext_vector_type(4))) float f32x4;
typedef __attribute__((ext_vector_type(4))) int i32x4;
typedef __attribute__((ext_vector_type(8))) int i32x8;

#define LDS_PANEL_B 65536
#define LDS_RED     131072
#define LDS_TOTAL   139264

// ---------- prep: fp32 X -> fp8 e4m3 Xb (HW RNE cvt), sq from rounded values ----------

__global__ void krr_prep8(const float* __restrict__ X, u8* __restrict__ Xb,
                          float* __restrict__ sq) {
    const int rl  = threadIdx.x >> 4;
    const int l   = threadIdx.x & 15;
    const int row = blockIdx.x * 16 + rl;
    const float* src = X + (size_t)row * 256 + l * 16;

    float s = 0.f;
    int wv[4];
    #pragma unroll
    for (int c = 0; c < 4; ++c) {
        int pk = __builtin_amdgcn_cvt_pk_fp8_f32(src[c*4+0], src[c*4+1], 0, false);
        pk     = __builtin_amdgcn_cvt_pk_fp8_f32(src[c*4+2], src[c*4+3], pk, true);
        wv[c] = pk;
        float x0 = __builtin_amdgcn_cvt_f32_fp8(pk, 0);
        float x1 = __builtin_amdgcn_cvt_f32_fp8(pk, 1);
        float x2 = __builtin_amdgcn_cvt_f32_fp8(pk, 2);
        float x3 = __builtin_amdgcn_cvt_f32_fp8(pk, 3);
        s = fmaf(x0, x0, s);
        s = fmaf(x1, x1, s);
        s = fmaf(x2, x2, s);
        s = fmaf(x3, x3, s);
    }
    *reinterpret_cast<i32x4*>(Xb + (size_t)row * 256 + l * 16) =
        (i32x4){wv[0], wv[1], wv[2], wv[3]};

    s += __shfl_xor(s, 1, 16);
    s += __shfl_xor(s, 2, 16);
    s += __shfl_xor(s, 4, 16);
    s += __shfl_xor(s, 8, 16);
    if (l == 0) sq[row] = s;
}

// ---------- big-tile symmetric kernel: 256x256, full K, MX-fp8 16x16x128, no atomics ----------
// Grid 512: bid<16 -> two diagonal tiles (scheduled first, extra length hides in round 1);
// bid>=16 -> off-diag tile (bid-16). Unified job loop, single inlined code path.
// Panels: linear 256B rows, 16B chunk slot c holds global chunk c^(r&15) (involution).

__global__ __launch_bounds__(1024, 4) void krr_big4(
    const u8* __restrict__ Xb, const float* __restrict__ sq,
    const float* __restrict__ alpha, float* __restrict__ P, int N)
{
    extern __shared__ __align__(16) u8 lds[];
    float* rowredf = (float*)(lds + LDS_RED);          // [4][256]
    float* colredf = rowredf + 1024;                   // [4][256]

    const int bid  = blockIdx.x;
    const int tid  = threadIdx.x;
    const int lane = tid & 63;
    const int w    = tid >> 6;           // 0..15, 4x4 wave grid
    const int wr   = (w >> 2) * 64;
    const int wc   = (w & 3) * 64;
    const int g    = lane >> 4;          // 0..3: 32B k-window within a 128-K block
    const int rl   = lane & 15;
    const int T    = N >> 8;             // 32
    const int nDiagBlk = T >> 1;         // 16 blocks handle 2 diagonals each

    // job setup
    int njobs, jrb[2], jcb[2];
    bool jod;
    if (bid < nDiagBlk) {
        njobs = 2;
        jrb[0] = (2 * bid) << 8;     jcb[0] = jrb[0];
        jrb[1] = (2 * bid + 1) << 8; jcb[1] = jrb[1];
        jod = false;
    } else {
        njobs = 1;
        const int t = bid - nDiagBlk;
        float Tf = (float)T - 0.5f;
        int ti = (int)(Tf - sqrtf(fmaxf(Tf * Tf - 2.0f * (float)t, 0.f)));
        if (ti < 0) ti = 0;
        if (ti > T - 2) ti = T - 2;
        while ((ti + 1) * T - ((ti + 1) * (ti + 2)) / 2 <= t) ++ti;
        while (ti * T - (ti * (ti + 1)) / 2 > t) --ti;
        int tj = ti + 1 + (t - (ti * T - (ti * (ti + 1)) / 2));
        jrb[0] = ti << 8; jcb[0] = tj << 8;
        jrb[1] = jrb[0];  jcb[1] = jcb[0];
        jod = true;
    }

    for (int jb = 0; jb < njobs; ++jb) {
        const int rb = jrb[jb], cb = jcb[jb];
        const bool od = jod;
        const int bofs = od ? LDS_PANEL_B : 0;

        // ---- stage: linear coalesced global reads -> swizzled b128 LDS writes ----
        {
            i32x4 rg[4];
            #pragma unroll
            for (int it = 0; it < 4; ++it) {
                int idx = it * 1024 + tid;
                int r = idx >> 4, c = idx & 15;
                rg[it] = *reinterpret_cast<const i32x4*>(&Xb[(size_t)(rb + r) * 256 + c * 16]);
            }
            #pragma unroll
            for (int it = 0; it < 4; ++it) {
                int idx = it * 1024 + tid;
                int r = idx >> 4, c = idx & 15;
                *reinterpret_cast<i32x4*>(&lds[r * 256 + ((c ^ (r & 15)) << 4)]) = rg[it];
            }
            if (od) {
                #pragma unroll
                for (int it = 0; it < 4; ++it) {
                    int idx = it * 1024 + tid;
                    int r = idx >> 4, c = idx & 15;
                    rg[it] = *reinterpret_cast<const i32x4*>(&Xb[(size_t)(cb + r) * 256 + c * 16]);
                }
                #pragma unroll
                for (int it = 0; it < 4; ++it) {
                    int idx = it * 1024 + tid;
                    int r = idx >> 4, c = idx & 15;
                    *reinterpret_cast<i32x4*>(&lds[LDS_PANEL_B + r * 256 + ((c ^ (r & 15)) << 4)]) = rg[it];
                }
            }
        }
        __syncthreads();

        // ---- compute: MX-fp8 16x16x128, unit scales; 32 MFMA per wave ----
        f32x4 acc[4][4];
        #pragma unroll
        for (int m = 0; m < 4; ++m)
            #pragma unroll
            for (int n = 0; n < 4; ++n)
                acc[m][n] = (f32x4){0.f, 0.f, 0.f, 0.f};

        #pragma unroll
        for (int kq = 0; kq < 2; ++kq) {
            i32x8 a[4];
            #pragma unroll
            for (int m = 0; m < 4; ++m) {
                const u8* row = &lds[(wr + m * 16 + rl) * 256];
                i32x4 lo = *reinterpret_cast<const i32x4*>(row + (((kq * 8 + 2 * g)     ^ rl) << 4));
                i32x4 hi = *reinterpret_cast<const i32x4*>(row + (((kq * 8 + 2 * g + 1) ^ rl) << 4));
                a[m][0] = lo[0]; a[m][1] = lo[1]; a[m][2] = lo[2]; a[m][3] = lo[3];
                a[m][4] = hi[0]; a[m][5] = hi[1]; a[m][6] = hi[2]; a[m][7] = hi[3];
            }
            #pragma unroll
            for (int n = 0; n < 4; ++n) {
                const u8* row = &lds[bofs + (wc + n * 16 + rl) * 256];
                i32x4 lo = *reinterpret_cast<const i32x4*>(row + (((kq * 8 + 2 * g)     ^ rl) << 4));
                i32x4 hi = *reinterpret_cast<const i32x4*>(row + (((kq * 8 + 2 * g + 1) ^ rl) << 4));
                i32x8 b;
                b[0] = lo[0]; b[1] = lo[1]; b[2] = lo[2]; b[3] = lo[3];
                b[4] = hi[0]; b[5] = hi[1]; b[6] = hi[2]; b[7] = hi[3];
                #pragma unroll
                for (int m = 0; m < 4; ++m)
                    acc[m][n] = __builtin_amdgcn_mfma_scale_f32_16x16x128_f8f6f4(
                        a[m], b, acc[m][n], 0, 0,
                        0, 0x7f7f7f7f, 0, 0x7f7f7f7f);   // unit scales (E8M0 127)
            }
        }

        // ---- epilogue A: d2 -> exp -> *alpha -> partials into reduce areas ----
        {
            float sqc[4], alc[4];
            #pragma unroll
            for (int n = 0; n < 4; ++n) {
                int c = cb + wc + n * 16 + rl;
                sqc[n] = sq[c];
                alc[n] = alpha[c];
            }
            float csum[4] = {0.f, 0.f, 0.f, 0.f};
            float rowKeep[4] = {0.f, 0.f, 0.f, 0.f};
            #pragma unroll
            for (int m = 0; m < 4; ++m) {
                int r0 = rb + wr + m * 16 + g * 4;
                #pragma unroll
                for (int reg = 0; reg < 4; ++reg) {
                    float sqr = sq[r0 + reg];
                    float ar  = alpha[r0 + reg];
                    float s = 0.f;
                    #pragma unroll
                    for (int n = 0; n < 4; ++n) {
                        float d2 = sqr + sqc[n] - 2.0f * acc[m][n][reg];
                        d2 = fmaxf(d2, 0.f);
                        float k = __expf(-d2);
                        s += k * alc[n];
                        csum[n] = fmaf(k, ar, csum[n]);
                    }
                    s += __shfl_xor(s, 1, 16);
                    s += __shfl_xor(s, 2, 16);
                    s += __shfl_xor(s, 4, 16);
                    s += __shfl_xor(s, 8, 16);       // uniform over 16-lane group
                    if (reg == rl) rowKeep[m] = s;   // lanes rl<4 hold reg==rl
                }
            }
            #pragma unroll
            for (int n = 0; n < 4; ++n) {
                csum[n] += __shfl_xor(csum[n], 16, 64);
                csum[n] += __shfl_xor(csum[n], 32, 64);
                if (g == 0)
                    colredf[(w >> 2) * 256 + wc + n * 16 + rl] = csum[n];
            }
            if (rl < 4) {
                #pragma unroll
                for (int m = 0; m < 4; ++m)
                    rowredf[(w & 3) * 256 + wr + m * 16 + g * 4 + rl] = rowKeep[m];
            }
        }
        __syncthreads();

        // ---- epilogue B: gather partials, plain disjoint stores to P ----
        if (tid < 256) {
            float v = rowredf[tid] + rowredf[256 + tid] + rowredf[512 + tid] + rowredf[768 + tid];
            P[(size_t)(cb >> 8) * N + rb + tid] = v;
        } else if (tid < 512 && od) {
            int c = tid - 256;
            float v = colredf[c] + colredf[256 + c] + colredf[512 + c] + colredf[768 + c];
            P[(size_t)(rb >> 8) * N + cb + c] = v;
        }
        // next job's stage is ordered after this epiB by the post-stage barrier
    }
}

// ---------- final reduce: out[i] = sum_c P[c][i] (vectorized, no atomics) ----------

__global__ void krr_reduce(const f32x4* __restrict__ Pv, f32x4* __restrict__ outv,
                           int nvec, int T) {
    const int i = blockIdx.x * 256 + threadIdx.x;
    f32x4 s = (f32x4){0.f, 0.f, 0.f, 0.f};
    for (int c = 0; c < T; ++c) s += Pv[(size_t)c * nvec + i];
    outv[i] = s;
}

// ---------- fallback: honest fp32, slow ----------

__global__ void krr_naive(const float* __restrict__ X, const float* __restrict__ alpha,
                          float* __restrict__ out, int N, int D) {
    __shared__ float xi[256];
    const int i = blockIdx.x;
    const int t = threadIdx.x;
    for (int k = t; k < D; k += blockDim.x) xi[k] = X[(size_t)i * D + k];
    __syncthreads();
    float s = 0.f;
    for (int j = t; j < N; j += blockDim.x) {
        float d2 = 0.f;
        const float* xj = &X[(size_t)j * D];
        for (int k = 0; k < D; ++k) {
            float d = xi[k] - xj[k];
            d2 = fmaf(d, d, d2);
        }
        s += __expf(-fmaxf(d2, 0.f)) * alpha[j];
    }
    #pragma unroll
    for (int off = 32; off > 0; off >>= 1) s += __shfl_xor(s, off, 64);
    __shared__ float red[4];
    const int lane = t & 63, w = t >> 6;
    if (lane == 0) red[w] = s;
    __syncthreads();
    if (t == 0) out[i] = red[0] + red[1] + red[2] + red[3];
}

// ---------- launch ----------

extern "C" void kernel_launch(void* const* d_in, const int* in_sizes, int n_in,
                              void* d_out, int out_size, void* d_ws, size_t ws_size,
                              hipStream_t stream) {
    const float* X     = (const float*)d_in[0];
    const float* alpha = (const float*)d_in[1];
    float* out = (float*)d_out;

    const int N = in_sizes[1];           // 8192
    const int D = in_sizes[0] / N;       // 256

    size_t xb_bytes = (size_t)N * D;                 // 2 MiB fp8
    size_t sq_bytes = (size_t)N * sizeof(float);     // 32 KiB
    const int T = N >> 8;                            // 32
    size_t p_bytes  = (size_t)T * N * sizeof(float); // 1 MiB
    size_t need     = xb_bytes + sq_bytes + p_bytes;

    // grid plan (16 diag-pair + 496 off-diag) is specific to T=32
    bool shapes_ok = (D == 256) && (N == 8192) && (N == out_size);

    hipError_t e = hipFuncSetAttribute(
        reinterpret_cast<const void*>(krr_big4),
        hipFuncAttributeMaxDynamicSharedMemorySize, LDS_TOTAL);

    if (ws_size >= need && shapes_ok && e == hipSuccess) {
        u8*    Xb = (u8*)d_ws;
        float* sq = (float*)((char*)d_ws + xb_bytes);
        float* P  = (float*)((char*)d_ws + xb_bytes + sq_bytes);
        krr_prep8<<<N / 16, 256, 0, stream>>>(X, Xb, sq);
        krr_big4<<<512, 1024, LDS_TOTAL, stream>>>(Xb, sq, alpha, P, N);
        krr_reduce<<<N / 1024, 256, 0, stream>>>((const f32x4*)P, (f32x4*)out, N / 4, T);
    } else {
        (void)hipMemsetAsync(d_out, 0, (size_t)out_size * sizeof(float), stream);
        krr_naive<<<N, 256, 0, stream>>>(X, alpha, out, N, D);
    }
}

// Round 14
// 56.799 us; speedup vs baseline: 1.1980x; 1.1980x over previous
//
#include <hip/hip_runtime.h>

typedef unsigned char u8;
typedef __attribute__((ext_vector_type(4))) float f32x4;
typedef __attribute__((ext_vector_type(4))) int i32x4;
typedef __attribute__((ext_vector_type(2))) long long2v;

#define LDS_PANEL_B 65536
#define LDS_COLRED  131072
#define LDS_TOTAL   135168
#define RRSTRIDE    264          // dwords; 264%32=8 -> balanced b128 partial writes

// ---------- prep: fp32 X -> fp8 e4m3 Xb (HW RNE cvt), sq from rounded values ----------

__global__ void krr_prep8(const float* __restrict__ X, u8* __restrict__ Xb,
                          float* __restrict__ sq) {
    const int rl  = threadIdx.x >> 4;
    const int l   = threadIdx.x & 15;
    const int row = blockIdx.x * 16 + rl;
    const float* src = X + (size_t)row * 256 + l * 16;

    float s = 0.f;
    int wv[4];
    #pragma unroll
    for (int c = 0; c < 4; ++c) {
        int pk = __builtin_amdgcn_cvt_pk_fp8_f32(src[c*4+0], src[c*4+1], 0, false);
        pk     = __builtin_amdgcn_cvt_pk_fp8_f32(src[c*4+2], src[c*4+3], pk, true);
        wv[c] = pk;
        float x0 = __builtin_amdgcn_cvt_f32_fp8(pk, 0);
        float x1 = __builtin_amdgcn_cvt_f32_fp8(pk, 1);
        float x2 = __builtin_amdgcn_cvt_f32_fp8(pk, 2);
        float x3 = __builtin_amdgcn_cvt_f32_fp8(pk, 3);
        s = fmaf(x0, x0, s);
        s = fmaf(x1, x1, s);
        s = fmaf(x2, x2, s);
        s = fmaf(x3, x3, s);
    }
    *reinterpret_cast<i32x4*>(Xb + (size_t)row * 256 + l * 16) =
        (i32x4){wv[0], wv[1], wv[2], wv[3]};

    s += __shfl_xor(s, 1, 16);
    s += __shfl_xor(s, 2, 16);
    s += __shfl_xor(s, 4, 16);
    s += __shfl_xor(s, 8, 16);
    if (l == 0) sq[row] = s;
}

// ---------- big-tile symmetric kernel: 256x256, fp8 16x16x32, b128-pair frags, no atomics ----
// Panels: 256B rows, 16B chunk slot = c ^ (r&15) (R12-measured 0 conflicts).
// k-permutation: logical chunk kp*4+g holds lane g's operands for k-steps {2kp, 2kp+1}
// (dot-product invariant under shared k relabeling; A and B use the same rule).

__global__ __launch_bounds__(1024) void krr_big5(
    const u8* __restrict__ Xb, const float* __restrict__ sq,
    const float* __restrict__ alpha, float* __restrict__ P, int N)
{
    extern __shared__ __align__(16) u8 lds[];
    float* rowredf = (float*)lds;                      // [64][RRSTRIDE] dwords, overlays panels
    float* colredf = (float*)(lds + LDS_COLRED);       // [4][256]

    const int bid  = blockIdx.x;
    const int tid  = threadIdx.x;
    const int lane = tid & 63;
    const int w    = tid >> 6;           // 0..15, 4x4 wave grid
    const int wr   = (w >> 2) * 64;
    const int wc   = (w & 3) * 64;
    const int g    = lane >> 4;          // 0..3
    const int rl   = lane & 15;
    const int T    = N >> 8;             // 32
    const int nOff = T * (T - 1) / 2;    // 496

    f32x4 acc[4][4];

    // ---- stage one panel: linear coalesced reads -> chunk-XOR swizzled b128 LDS writes ----
    auto stage_panel = [&](int gbase, int pbase) {
        i32x4 rg[4];
        #pragma unroll
        for (int it = 0; it < 4; ++it) {
            int idx = it * 1024 + tid;
            int r = idx >> 4, c = idx & 15;
            rg[it] = *reinterpret_cast<const i32x4*>(&Xb[(size_t)(gbase + r) * 256 + c * 16]);
        }
        #pragma unroll
        for (int it = 0; it < 4; ++it) {
            int idx = it * 1024 + tid;
            int r = idx >> 4, c = idx & 15;
            *reinterpret_cast<i32x4*>(&lds[pbase + r * 256 + ((c ^ (r & 15)) << 4)]) = rg[it];
        }
    };

    // ---- compute: 4 kp blocks x {8 b128 frag reads, 32 MFMA} ----
    auto compute = [&](int bofs) {
        #pragma unroll
        for (int m = 0; m < 4; ++m)
            #pragma unroll
            for (int n = 0; n < 4; ++n)
                acc[m][n] = (f32x4){0.f, 0.f, 0.f, 0.f};
        #pragma unroll
        for (int kp = 0; kp < 4; ++kp) {
            const int lc = kp * 4 + g;               // logical chunk for this lane
            long2v a[4], b[4];
            #pragma unroll
            for (int m = 0; m < 4; ++m) {
                int r = wr + m * 16 + rl;
                a[m] = *reinterpret_cast<const long2v*>(&lds[r * 256 + ((lc ^ rl) << 4)]);
            }
            #pragma unroll
            for (int n = 0; n < 4; ++n) {
                int r = wc + n * 16 + rl;
                b[n] = *reinterpret_cast<const long2v*>(&lds[bofs + r * 256 + ((lc ^ rl) << 4)]);
            }
            #pragma unroll
            for (int m = 0; m < 4; ++m)
                #pragma unroll
                for (int n = 0; n < 4; ++n)
                    acc[m][n] = __builtin_amdgcn_mfma_f32_16x16x32_fp8_fp8(
                        a[m][0], b[n][0], acc[m][n], 0, 0, 0);
            #pragma unroll
            for (int m = 0; m < 4; ++m)
                #pragma unroll
                for (int n = 0; n < 4; ++n)
                    acc[m][n] = __builtin_amdgcn_mfma_f32_16x16x32_fp8_fp8(
                        a[m][1], b[n][1], acc[m][n], 0, 0, 0);
        }
    };

    // ---- epilogue A: d2->exp->*alpha; in-thread n-sum -> b128 partial writes; col via 2 shfl ----
    auto epiA = [&](int rb, int cb, bool od) {
        float sqc[4], alc[4];
        #pragma unroll
        for (int n = 0; n < 4; ++n) {
            int c = cb + wc + n * 16 + rl;
            sqc[n] = sq[c];
            alc[n] = alpha[c];
        }
        float csum[4] = {0.f, 0.f, 0.f, 0.f};
        #pragma unroll
        for (int m = 0; m < 4; ++m) {
            f32x4 sv;
            #pragma unroll
            for (int reg = 0; reg < 4; ++reg) {
                int r = rb + wr + m * 16 + g * 4 + reg;
                float sqr = sq[r];
                float ar  = alpha[r];
                float s = 0.f;
                #pragma unroll
                for (int n = 0; n < 4; ++n) {
                    float d2 = sqr + sqc[n] - 2.0f * acc[m][n][reg];
                    d2 = fmaxf(d2, 0.f);
                    float k = __expf(-d2);
                    s += k * alc[n];
                    csum[n] = fmaf(k, ar, csum[n]);
                }
                sv[reg] = s;   // partial over this thread's 4 cols, row (m,reg)
            }
            // write 4 row-partials (consecutive rows) as one b128
            int slot = (w & 3) * 16 + rl;            // 64 contributor slots
            int rloc = wr + m * 16 + g * 4;          // row base within tile
            *reinterpret_cast<f32x4*>(&rowredf[slot * RRSTRIDE + rloc]) = sv;
        }
        #pragma unroll
        for (int n = 0; n < 4; ++n) {
            csum[n] += __shfl_xor(csum[n], 16, 64);
            csum[n] += __shfl_xor(csum[n], 32, 64);
            if (g == 0 && od)
                colredf[(w >> 2) * 256 + wc + n * 16 + rl] = csum[n];
        }
    };

    // ---- epilogue B: gather 64 partials per row, plain disjoint stores to P ----
    auto epiB = [&](int rb, int cb, bool od) {
        if (tid < 256) {
            float v0 = 0.f, v1 = 0.f, v2 = 0.f, v3 = 0.f;
            #pragma unroll
            for (int j = 0; j < 64; j += 4) {
                v0 += rowredf[(j    ) * RRSTRIDE + tid];
                v1 += rowredf[(j + 1) * RRSTRIDE + tid];
                v2 += rowredf[(j + 2) * RRSTRIDE + tid];
                v3 += rowredf[(j + 3) * RRSTRIDE + tid];
            }
            P[(size_t)(cb >> 8) * N + rb + tid] = (v0 + v1) + (v2 + v3);
        } else if (tid < 512 && od) {
            int c = tid - 256;
            float v = colredf[c] + colredf[256 + c] + colredf[512 + c] + colredf[768 + c];
            P[(size_t)(rb >> 8) * N + cb + c] = v;
        }
    };

    if (bid < nOff) {
        // ---- off-diagonal tile ----
        const int t = bid;
        float Tf = (float)T - 0.5f;
        int ti = (int)(Tf - sqrtf(fmaxf(Tf * Tf - 2.0f * (float)t, 0.f)));
        if (ti < 0) ti = 0;
        if (ti > T - 2) ti = T - 2;
        while ((ti + 1) * T - ((ti + 1) * (ti + 2)) / 2 <= t) ++ti;
        while (ti * T - (ti * (ti + 1)) / 2 > t) --ti;
        int tj = ti + 1 + (t - (ti * T - (ti * (ti + 1)) / 2));
        const int rb = ti << 8, cb = tj << 8;

        stage_panel(rb, 0);
        stage_panel(cb, LDS_PANEL_B);
        __syncthreads();
        compute(LDS_PANEL_B);
        __syncthreads();               // all frag reads done before rowred overlays panels
        epiA(rb, cb, true);
        __syncthreads();
        epiB(rb, cb, true);
    } else {
        // ---- diag-pair block: two half-work diagonal tiles ----
        const int d0 = 2 * (bid - nOff);
        #pragma unroll
        for (int jb = 0; jb < 2; ++jb) {
            const int rb = (d0 + jb) << 8;
            stage_panel(rb, 0);
            __syncthreads();
            compute(0);
            __syncthreads();
            epiA(rb, rb, false);
            __syncthreads();
            epiB(rb, rb, false);
            __syncthreads();           // rowred read done before next stage clobbers
        }
    }
}

// ---------- final reduce: out[i] = sum_c P[c][i] (vectorized, no atomics) ----------

__global__ void krr_reduce(const f32x4* __restrict__ Pv, f32x4* __restrict__ outv,
                           int nvec, int T) {
    const int i = blockIdx.x * 256 + threadIdx.x;
    f32x4 s = (f32x4){0.f, 0.f, 0.f, 0.f};
    for (int c = 0; c < T; ++c) s += Pv[(size_t)c * nvec + i];
    outv[i] = s;
}

// ---------- fallback: honest fp32, slow ----------

__global__ void krr_naive(const float* __restrict__ X, const float* __restrict__ alpha,
                          float* __restrict__ out, int N, int D) {
    __shared__ float xi[256];
    const int i = blockIdx.x;
    const int t = threadIdx.x;
    for (int k = t; k < D; k += blockDim.x) xi[k] = X[(size_t)i * D + k];
    __syncthreads();
    float s = 0.f;
    for (int j = t; j < N; j += blockDim.x) {
        float d2 = 0.f;
        const float* xj = &X[(size_t)j * D];
        for (int k = 0; k < D; ++k) {
            float d = xi[k] - xj[k];
            d2 = fmaf(d, d, d2);
        }
        s += __expf(-fmaxf(d2, 0.f)) * alpha[j];
    }
    #pragma unroll
    for (int off = 32; off > 0; off >>= 1) s += __shfl_xor(s, off, 64);
    __shared__ float red[4];
    const int lane = t & 63, w = t >> 6;
    if (lane == 0) red[w] = s;
    __syncthreads();
    if (t == 0) out[i] = red[0] + red[1] + red[2] + red[3];
}

// ---------- launch ----------

extern "C" void kernel_launch(void* const* d_in, const int* in_sizes, int n_in,
                              void* d_out, int out_size, void* d_ws, size_t ws_size,
                              hipStream_t stream) {
    const float* X     = (const float*)d_in[0];
    const float* alpha = (const float*)d_in[1];
    float* out = (float*)d_out;

    const int N = in_sizes[1];           // 8192
    const int D = in_sizes[0] / N;       // 256

    size_t xb_bytes = (size_t)N * D;                 // 2 MiB fp8
    size_t sq_bytes = (size_t)N * sizeof(float);     // 32 KiB
    const int T = N >> 8;                            // 32
    size_t p_bytes  = (size_t)T * N * sizeof(float); // 1 MiB
    size_t need     = xb_bytes + sq_bytes + p_bytes;

    // grid plan (496 off-diag + 16 diag-pair) is specific to T=32
    bool shapes_ok = (D == 256) && (N == 8192) && (N == out_size);

    hipError_t e = hipFuncSetAttribute(
        reinterpret_cast<const void*>(krr_big5),
        hipFuncAttributeMaxDynamicSharedMemorySize, LDS_TOTAL);

    if (ws_size >= need && shapes_ok && e == hipSuccess) {
        u8*    Xb = (u8*)d_ws;
        float* sq = (float*)((char*)d_ws + xb_bytes);
        float* P  = (float*)((char*)d_ws + xb_bytes + sq_bytes);
        krr_prep8<<<N / 16, 256, 0, stream>>>(X, Xb, sq);
        krr_big5<<<512, 1024, LDS_TOTAL, stream>>>(Xb, sq, alpha, P, N);
        krr_reduce<<<N / 1024, 256, 0, stream>>>((const f32x4*)P, (f32x4*)out, N / 4, T);
    } else {
        (void)hipMemsetAsync(d_out, 0, (size_t)out_size * sizeof(float), stream);
        krr_naive<<<N, 256, 0, stream>>>(X, alpha, out, N, D);
    }
}